// Round 1
// baseline (498.247 us; speedup 1.0000x reference)
//
#include <hip/hip_runtime.h>

// Fern patch-descriptor pipeline, fully fused single kernel.
//   x:(64,8,128,128) f32, thresholds:(8,12) f32, table:(8,4096,32) f32,
//   chan_idx:(8,12,2) i32, offsets:(8,12,2,2) i32
//   out:(64, 32*114*114) f32
//
// Tile design: output tile 19x19 (114 = 6*19 exact), positions tile 25x25,
// x tile 8ch x 33x33.  LDS = 34848B (x) + 90000B (votes, stride 36 floats for
// 16B-aligned float4 rows) = 124848B -> dynamic LDS, 1 block/CU, 512 thr.
// Grid = 64 images * 36 tiles = 2304 blocks = 9 * 256 CUs exactly.

#define NN 64
#define CC 8
#define HH 128
#define WW 128
#define MM 8
#define KK 12
#define DD 32
#define HPP 120
#define OUTS 114
#define TT 19          // output tile edge
#define PT 25          // position tile edge = TT + POOL - 1
#define XT 33          // x tile edge = PT + L - 1
#define XSTRIDE (XT*XT)   // 1089
#define VSTRIDE 36        // vote row stride (pad 32 -> 36, keeps 16B align)
#define NPOSI (PT*PT)     // 625
#define THREADS 512
#define POOLW 7

#define LDS_FLOATS (CC*XSTRIDE + NPOSI*VSTRIDE)   // 8712 + 22500 = 31212
#define LDS_BYTES  (LDS_FLOATS*4)                 // 124848

__global__ __launch_bounds__(THREADS, 1)
void fern_fused(const float* __restrict__ x,
                const float* __restrict__ thresholds,
                const float* __restrict__ table,
                const int*   __restrict__ chan_idx,
                const int*   __restrict__ offsets,
                float* __restrict__ out)
{
    extern __shared__ float smem[];
    float* xs = smem;                    // [8][33][33]
    float* vs = smem + CC*XSTRIDE;       // [625][36]

    const int tile = blockIdx.x;         // 0..2303
    const int n    = tile / 36;
    const int t2   = tile - n*36;
    const int ti   = t2 / 6;
    const int tj   = t2 - ti*6;
    const int i0   = ti * TT;            // 0..95
    const int j0   = tj * TT;

    const int tid = threadIdx.x;

    // ---------------- Phase 1: stage x tile into LDS ----------------
    // rows i0..i0+32 <= 127 and cols j0..j0+32 <= 127 exactly: no clamping.
    const float* xn = x + (size_t)n * (CC*HH*WW);
    for (int idx = tid; idx < CC*XSTRIDE; idx += THREADS) {
        int c   = idx / XSTRIDE;
        int rem = idx - c*XSTRIDE;
        int r   = rem / XT;
        int col = rem - r*XT;
        xs[idx] = xn[(c*HH + (i0 + r))*WW + (j0 + col)];
    }
    __syncthreads();

    // ---------------- Phase 2: per-position fern votes into LDS ----------------
    for (int p = tid; p < NPOSI; p += THREADS) {
        int y  = p / PT;
        int j  = p - y*PT;
        int pb = y*XT + j;

        float vote[DD];
        #pragma unroll
        for (int d = 0; d < DD; ++d) vote[d] = 0.f;

        #pragma unroll
        for (int m = 0; m < MM; ++m) {
            unsigned word = 0u;
            float P = 1.f;                    // prod(1 + exp(-10|z|))
            #pragma unroll
            for (int k = 0; k < KK; ++k) {
                const int mk = m*KK + k;
                // wave-uniform (compile-time mk) -> scalar loads
                int c1  = chan_idx[mk*2 + 0];
                int c2  = chan_idx[mk*2 + 1];
                int dy1 = offsets[mk*4 + 0];
                int dx1 = offsets[mk*4 + 1];
                int dy2 = offsets[mk*4 + 2];
                int dx2 = offsets[mk*4 + 3];
                float thr = thresholds[mk];
                float p1 = xs[c1*XSTRIDE + dy1*XT + dx1 + pb];
                float p2 = xs[c2*XSTRIDE + dy2*XT + dx2 + pb];
                float z  = (p1 - p2) - thr;
                if (z > 0.f) word |= (1u << k);
                float e = __expf(-10.f * fabsf(z));
                P += P * e;                   // P *= (1+e), single v_fma
            }
            float cf = __builtin_amdgcn_rcpf(P);   // conf = 1/P, 1-ulp rcp
            const float4* t = (const float4*)(table + (((size_t)m << 12) + word)*DD);
            #pragma unroll
            for (int d4 = 0; d4 < DD/4; ++d4) {
                float4 tv = t[d4];
                vote[d4*4+0] += cf * tv.x;
                vote[d4*4+1] += cf * tv.y;
                vote[d4*4+2] += cf * tv.z;
                vote[d4*4+3] += cf * tv.w;
            }
        }

        float4* vrow = (float4*)(vs + p*VSTRIDE);
        #pragma unroll
        for (int d4 = 0; d4 < DD/4; ++d4) {
            vrow[d4] = make_float4(vote[d4*4+0], vote[d4*4+1],
                                   vote[d4*4+2], vote[d4*4+3]);
        }
    }
    __syncthreads();

    // ---------------- Phase 3a: horizontal 7-window running sums (in-place) ----
    // work item = (y, d4): 25*8 = 200 items
    for (int w = tid; w < PT*8; w += THREADS) {
        int y  = w / 8;
        int d4 = w - y*8;
        float4 s = make_float4(0.f, 0.f, 0.f, 0.f);
        float4 ring[POOLW];
        #pragma unroll
        for (int j = 0; j < PT; ++j) {
            float4 v = *(const float4*)(vs + (y*PT + j)*VSTRIDE + d4*4);
            if (j >= POOLW) {
                float4 o = ring[j % POOLW];
                s.x -= o.x; s.y -= o.y; s.z -= o.z; s.w -= o.w;
            }
            ring[j % POOLW] = v;
            s.x += v.x; s.y += v.y; s.z += v.z; s.w += v.w;
            if (j >= POOLW-1) {
                // write index j-6 < j: already consumed, safe in-place
                *(float4*)(vs + (y*PT + (j - POOLW + 1))*VSTRIDE + d4*4) = s;
            }
        }
    }
    __syncthreads();

    // ---------------- Phase 3b: vertical 7-window + store -----------------
    // work item = (d4, jo) with jo fastest for store coalescing: 8*19 = 152
    const float inv = 1.f / 49.f;
    float* outn = out + (size_t)n * (DD*OUTS*OUTS);
    for (int w = tid; w < 8*TT; w += THREADS) {
        int d4 = w / TT;
        int jo = w - d4*TT;
        float4 s = make_float4(0.f, 0.f, 0.f, 0.f);
        float4 ring[POOLW];
        #pragma unroll
        for (int y = 0; y < PT; ++y) {
            float4 v = *(const float4*)(vs + (y*PT + jo)*VSTRIDE + d4*4);
            if (y >= POOLW) {
                float4 o = ring[y % POOLW];
                s.x -= o.x; s.y -= o.y; s.z -= o.z; s.w -= o.w;
            }
            ring[y % POOLW] = v;
            s.x += v.x; s.y += v.y; s.z += v.z; s.w += v.w;
            if (y >= POOLW-1) {
                int io = y - POOLW + 1;
                size_t base = ((size_t)(d4*4)*OUTS + (i0 + io))*OUTS + (j0 + jo);
                outn[base                 ] = s.x * inv;
                outn[base +   (size_t)OUTS*OUTS] = s.y * inv;
                outn[base + 2*(size_t)OUTS*OUTS] = s.z * inv;
                outn[base + 3*(size_t)OUTS*OUTS] = s.w * inv;
            }
        }
    }
}

extern "C" void kernel_launch(void* const* d_in, const int* in_sizes, int n_in,
                              void* d_out, int out_size, void* d_ws, size_t ws_size,
                              hipStream_t stream) {
    const float* x          = (const float*)d_in[0];
    const float* thresholds = (const float*)d_in[1];
    const float* table      = (const float*)d_in[2];
    const int*   chan_idx   = (const int*)d_in[3];
    const int*   offsets    = (const int*)d_in[4];
    float* out = (float*)d_out;

    // dynamic LDS > 64KB needs the opt-in attribute (idempotent, capture-safe)
    static bool attr_set = false;   // setting an attribute is global state, not work
    hipFuncSetAttribute((const void*)fern_fused,
                        hipFuncAttributeMaxDynamicSharedMemorySize, LDS_BYTES);

    dim3 grid(NN * 36);
    dim3 block(THREADS);
    fern_fused<<<grid, block, LDS_BYTES, stream>>>(x, thresholds, table,
                                                   chan_idx, offsets, out);
}